// Round 8
// baseline (264.666 us; speedup 1.0000x reference)
//
#include <hip/hip_runtime.h>

// ---------------------------------------------------------------------------
// DCINet: 3-layer GraphSAGE (mean aggr) + degree embedding encoder + MLP head.
// N=50000, E=800000, H=128.
// R8: fused per-layer kernel — gather+mean -> swizzled LDS tile -> MFMA GEMM
//     (+ fused head on layer 3, wave-private LDS rows, no barrier). agg and
//     h3 never hit global memory. CSR counting-sort build as R7 (u16 CSR).
// ---------------------------------------------------------------------------

#define HDIM 128
#define NB 256          // binning blocks
#define MAXBUK 512      // max buckets (N <= 65536)
#define SCH 4096        // elements per scan block (256 thr x 16)

typedef __attribute__((ext_vector_type(8))) short short8;   // 8 bf16 (4 VGPR)
typedef __attribute__((ext_vector_type(4))) float f32x4;

__device__ inline float bf2f(unsigned short u) {
    union { unsigned int u; float f; } t; t.u = (unsigned int)u << 16; return t.f;
}
__device__ inline unsigned short f2bf(float f) {           // round-to-nearest-even
    union { float f; unsigned int u; } t; t.f = f;
    unsigned int u = t.u;
    return (unsigned short)((u + 0x7FFFu + ((u >> 16) & 1u)) >> 16);
}

// ---- phase 1: per-block LDS histograms over buckets (dst and src keys) -----

__global__ __launch_bounds__(256) void binhist_kernel(const int* __restrict__ src,
                                                      const int* __restrict__ dst,
                                                      int* __restrict__ hist,
                                                      int E, int nbuk, int ec) {
    __shared__ int hD[MAXBUK], hS[MAXBUK];
    const int tid = threadIdx.x, bid = blockIdx.x;
    for (int i = tid; i < nbuk; i += 256) { hD[i] = 0; hS[i] = 0; }
    __syncthreads();
    const int s0 = bid * ec, s1 = min(E, s0 + ec);
    for (int e = s0 + tid; e < s1; e += 256) {
        atomicAdd(&hD[dst[e] >> 7], 1);
        atomicAdd(&hS[src[e] >> 7], 1);
    }
    __syncthreads();
    for (int i = tid; i < nbuk; i += 256) {
        hist[(size_t)i * NB + bid] = hD[i];
        hist[(size_t)(nbuk + i) * NB + bid] = hS[i];
    }
}

// ---- phase 2: exclusive scan over hist[L], L = 2*nbuk*NB -------------------

__global__ __launch_bounds__(256) void hscan1_kernel(const int* __restrict__ a,
                                                     int* __restrict__ bsum, int L) {
    __shared__ int shw[4];
    const int tid = threadIdx.x;
    const int base = blockIdx.x * SCH + tid * 16;
    int s = 0;
#pragma unroll
    for (int j = 0; j < 16; ++j) { int i = base + j; if (i < L) s += a[i]; }
#pragma unroll
    for (int off = 32; off > 0; off >>= 1) s += __shfl_down(s, off, 64);
    if ((tid & 63) == 0) shw[tid >> 6] = s;
    __syncthreads();
    if (tid == 0) bsum[blockIdx.x] = shw[0] + shw[1] + shw[2] + shw[3];
}

__global__ void hscan2_kernel(int* __restrict__ bsum, int nb) {
    int lane = threadIdx.x;
    int v = (lane < nb) ? bsum[lane] : 0;
    int orig = v;
#pragma unroll
    for (int off = 1; off < 64; off <<= 1) {
        int t = __shfl_up(v, off, 64);
        if (lane >= off) v += t;
    }
    if (lane < nb) bsum[lane] = v - orig;      // exclusive
}

__global__ __launch_bounds__(256) void hscan3_kernel(const int* __restrict__ a,
                                                     const int* __restrict__ bsum,
                                                     int* __restrict__ out, int L) {
    __shared__ int shw[4];
    const int tid = threadIdx.x;
    const int lane = tid & 63;
    const int w = tid >> 6;
    const int base = blockIdx.x * SCH + tid * 16;
    int v[16];
    int s = 0;
#pragma unroll
    for (int j = 0; j < 16; ++j) {
        int i = base + j;
        v[j] = (i < L) ? a[i] : 0;
        s += v[j];
    }
    int incl = s;
#pragma unroll
    for (int off = 1; off < 64; off <<= 1) {
        int t = __shfl_up(incl, off, 64);
        if (lane >= off) incl += t;
    }
    if (lane == 63) shw[w] = incl;
    __syncthreads();
    int woff = 0;
#pragma unroll
    for (int j = 0; j < 4; ++j) if (j < w) woff += shw[j];
    int pfx = bsum[blockIdx.x] + woff + incl - s;
#pragma unroll
    for (int j = 0; j < 16; ++j) {
        int i = base + j;
        if (i < L) out[i] = pfx;
        pfx += v[j];
    }
}

// ---- phase 3: scatter edges into bucket-sorted arrays (LDS cursors) --------

__global__ __launch_bounds__(256) void binscatter_kernel(const int* __restrict__ src,
                                                         const int* __restrict__ dst,
                                                         const int* __restrict__ scanned,
                                                         unsigned int* __restrict__ binD,
                                                         unsigned char* __restrict__ binS,
                                                         int E, int nbuk, int ec) {
    __shared__ int curD[MAXBUK], curS[MAXBUK];
    const int tid = threadIdx.x, bid = blockIdx.x;
    for (int i = tid; i < nbuk; i += 256) {
        curD[i] = scanned[(size_t)i * NB + bid];
        curS[i] = scanned[(size_t)(nbuk + i) * NB + bid] - E;
    }
    __syncthreads();
    const int s0 = bid * ec, s1 = min(E, s0 + ec);
    for (int e = s0 + tid; e < s1; e += 256) {
        int s = src[e], d = dst[e];
        int pd = atomicAdd(&curD[d >> 7], 1);
        binD[pd] = (unsigned int)s | ((unsigned int)(d & 127) << 16);
        int ps = atomicAdd(&curS[s >> 7], 1);
        binS[ps] = (unsigned char)(s & 127);
    }
}

// ---- phase 4: per-bucket finalize -> rowptr, outdeg, u16 CSR ---------------

__global__ __launch_bounds__(256) void finalize_kernel(const unsigned int* __restrict__ binD,
                                                       const unsigned char* __restrict__ binS,
                                                       const int* __restrict__ scanned,
                                                       unsigned short* __restrict__ csr,
                                                       int* __restrict__ rowptr,
                                                       int* __restrict__ outdeg,
                                                       int E, int n, int nbuk) {
    __shared__ int cntD[128], cur[128], cntS[128];
    const int b = blockIdx.x, tid = threadIdx.x;
    if (tid < 128) { cntD[tid] = 0; cntS[tid] = 0; }
    __syncthreads();
    const int s0 = scanned[(size_t)b * NB];
    const int s1 = (b == nbuk - 1) ? E : scanned[(size_t)(b + 1) * NB];
    const int t0 = scanned[(size_t)(nbuk + b) * NB] - E;
    const int t1 = (b == nbuk - 1) ? E : scanned[(size_t)(nbuk + b + 1) * NB] - E;
    for (int e = s0 + tid; e < s1; e += 256) atomicAdd(&cntD[(binD[e] >> 16) & 127], 1);
    for (int e = t0 + tid; e < t1; e += 256) atomicAdd(&cntS[binS[e]], 1);
    __syncthreads();
    if (tid < 128) cur[tid] = cntD[tid];
    __syncthreads();
    for (int off = 1; off < 128; off <<= 1) {
        int t = (tid < 128 && tid >= off) ? cur[tid - off] : 0;
        __syncthreads();
        if (tid < 128) cur[tid] += t;
        __syncthreads();
    }
    if (tid < 128) {
        int ex = cur[tid] - cntD[tid];
        int node = b * 128 + tid;
        if (node < n) { rowptr[node] = s0 + ex; outdeg[node] = cntS[tid]; }
        cur[tid] = ex;
    }
    __syncthreads();
    for (int e = s0 + tid; e < s1; e += 256) {
        unsigned int p = binD[e];
        int pos = atomicAdd(&cur[(p >> 16) & 127], 1);
        csr[s0 + pos] = (unsigned short)(p & 0xFFFFu);
    }
    if (b == 0 && tid == 0) rowptr[n] = E;
}

// ---- weight fp32 -> bf16: 6x[128][128] + Wh1[64][128], row-major kept ------

__global__ void wconv_kernel(const float* __restrict__ W1l, const float* __restrict__ W1r,
                             const float* __restrict__ W2l, const float* __restrict__ W2r,
                             const float* __restrict__ W3l, const float* __restrict__ W3r,
                             const float* __restrict__ Wh1,
                             unsigned short* __restrict__ out) {
    int idx = blockIdx.x * 256 + threadIdx.x;
    const float* s;
    int o;
    if (idx < 98304) {
        int m = idx >> 14; o = idx & 16383;
        switch (m) {
            case 0: s = W1l; break; case 1: s = W1r; break;
            case 2: s = W2l; break; case 3: s = W2r; break;
            case 4: s = W3l; break; default: s = W3r; break;
        }
    } else {
        s = Wh1; o = idx - 98304;
    }
    out[idx] = f2bf(s[o]);
}

// ---- encoder: h = relu(x*Wenc + benc + deg_emb[min(outdeg,199)]) -> bf16 ---

__global__ void encoder_kernel(const float* __restrict__ x, const float* __restrict__ Wenc,
                               const float* __restrict__ benc, const float* __restrict__ demb,
                               const int* __restrict__ outdeg,
                               unsigned short* __restrict__ h, int n) {
    int idx = blockIdx.x * blockDim.x + threadIdx.x;   // over n*16
    if (idx >= n * 16) return;
    int i = idx >> 4, g = idx & 15;
    int d = outdeg[i]; if (d > 199) d = 199;
    float xv = x[i];
    const float* wp = Wenc + g * 8;
    const float* bp = benc + g * 8;
    const float* ep = demb + (size_t)d * HDIM + g * 8;
    short8 o;
#pragma unroll
    for (int j = 0; j < 8; ++j)
        o[j] = (short)f2bf(fmaxf(xv * wp[j] + bp[j] + ep[j], 0.f));
    *(short8*)(h + (size_t)i * HDIM + g * 8) = o;
}

// ---- fused SAGE layer: gather+mean -> LDS (swizzled) -> MFMA -> out/head ----
// 512 thr = 8 waves, 128 nodes/block.
// Phase A: 32 groups x 16 lanes; group g does nodes g*4..g*4+3; 8-deep
//          clamped-unroll gather; mean -> bf16 -> sAgg with chunk XOR swizzle.
// Phase B: wave wv owns nodes wv*16..wv*16+15; swapped-operand MFMA
//          (A=weights from L2, B=node rows: agg from LDS, hin from global).
// HEAD:    h3 tile written back to own wave's LDS rows (no barrier needed),
//          then z=relu(h3@Wh1^T+bh1), scores=z@Wh2+bh2 via MFMA + shfl reduce.

template <bool RES, bool HEAD>
__global__ __launch_bounds__(512) void sage_fused(const unsigned short* __restrict__ hin,
                                                  const int* __restrict__ row_ptr,
                                                  const unsigned short* __restrict__ csr,
                                                  const unsigned short* __restrict__ Wl,
                                                  const unsigned short* __restrict__ Wr,
                                                  const float* __restrict__ bias,
                                                  unsigned short* __restrict__ outBf,
                                                  const unsigned short* __restrict__ Wh1b,
                                                  const float* __restrict__ bh1,
                                                  const float* __restrict__ Wh2,
                                                  const float* __restrict__ bh2,
                                                  float* __restrict__ scores, int n) {
    __shared__ unsigned short sAgg[128][128];
    const int t = threadIdx.x;
    const int row0b = blockIdx.x * 128;

    // ---- phase A: gather + mean ----
    {
        const int g = t >> 4;              // 0..31
        const int lg = t & 15;
        for (int jj = 0; jj < 4; ++jj) {
            const int j = g * 4 + jj;      // 0..127
            const int node = row0b + j;
            float a[8] = {};
            if (node < n) {
                const int beg = row_ptr[node];
                const int end = row_ptr[node + 1];
                for (int e = beg; e < end; e += 8) {
                    short8 v[8];
#pragma unroll
                    for (int u = 0; u < 8; ++u) {
                        int ee = e + u; if (ee > end - 1) ee = end - 1;
                        int sidx = csr[ee];
                        v[u] = *(const short8*)(hin + (size_t)sidx * HDIM + lg * 8);
                    }
#pragma unroll
                    for (int u = 0; u < 8; ++u) {
                        if (e + u < end) {
#pragma unroll
                            for (int k = 0; k < 8; ++k)
                                a[k] += bf2f((unsigned short)v[u][k]);
                        }
                    }
                }
                float inv = 1.f / fmaxf((float)(end - beg), 1.f);
#pragma unroll
                for (int k = 0; k < 8; ++k) a[k] *= inv;
            }
            short8 o;
#pragma unroll
            for (int k = 0; k < 8; ++k) o[k] = (short)f2bf(a[k]);
            *(short8*)(&sAgg[j][(lg ^ (j & 7)) * 8]) = o;
        }
    }
    __syncthreads();

    // ---- phase B: MFMA ----
    const int l = t & 63;
    const int wv = t >> 6;                 // 0..7
    const int l16 = l & 15;
    const int q = l >> 4;                  // 0..3
    const int lrow = wv * 16 + l16;        // local node 0..127
    const int node = row0b + lrow;
    const int cnode = min(node, n - 1);

    const unsigned short* wlp = Wl + (size_t)l16 * HDIM + q * 8;
    const unsigned short* wrp = Wr + (size_t)l16 * HDIM + q * 8;
    const unsigned short* hp = hin + (size_t)cnode * HDIM + q * 8;

    f32x4 acc[8] = {};
#pragma unroll
    for (int k0 = 0; k0 < 128; k0 += 32) {
        const int ch = q + (k0 >> 3);
        short8 xa = *(const short8*)(&sAgg[lrow][(ch ^ (lrow & 7)) * 8]);
        short8 xh = *(const short8*)(hp + k0);
#pragma unroll
        for (int ct = 0; ct < 8; ++ct) {
            short8 bl = *(const short8*)(wlp + (size_t)ct * 16 * HDIM + k0);
            short8 br = *(const short8*)(wrp + (size_t)ct * 16 * HDIM + k0);
            acc[ct] = __builtin_amdgcn_mfma_f32_16x16x32_bf16(bl, xa, acc[ct], 0, 0, 0);
            acc[ct] = __builtin_amdgcn_mfma_f32_16x16x32_bf16(br, xh, acc[ct], 0, 0, 0);
        }
    }

    if (!HEAD) {
        if (node < n) {
#pragma unroll
            for (int ct = 0; ct < 8; ++ct) {
                const int c0 = ct * 16 + q * 4;
                float4 bv = *(const float4*)(bias + c0);
                float v0 = fmaxf(acc[ct][0] + bv.x, 0.f);
                float v1 = fmaxf(acc[ct][1] + bv.y, 0.f);
                float v2 = fmaxf(acc[ct][2] + bv.z, 0.f);
                float v3 = fmaxf(acc[ct][3] + bv.w, 0.f);
                if (RES) {
                    uint2 rv = *(const uint2*)(hin + (size_t)cnode * HDIM + c0);
                    v0 += bf2f((unsigned short)(rv.x & 0xFFFF));
                    v1 += bf2f((unsigned short)(rv.x >> 16));
                    v2 += bf2f((unsigned short)(rv.y & 0xFFFF));
                    v3 += bf2f((unsigned short)(rv.y >> 16));
                }
                unsigned int o0 = (unsigned int)f2bf(v0) | ((unsigned int)f2bf(v1) << 16);
                unsigned int o1 = (unsigned int)f2bf(v2) | ((unsigned int)f2bf(v3) << 16);
                uint2 o; o.x = o0; o.y = o1;
                *(uint2*)(outBf + (size_t)node * HDIM + c0) = o;
            }
        }
        return;
    }

    // ---- fused head (layer 3): h3 -> own wave's LDS rows (no barrier) ------
#pragma unroll
    for (int ct = 0; ct < 8; ++ct) {
        const int c0 = ct * 16 + q * 4;
        float4 bv = *(const float4*)(bias + c0);
        float v0 = fmaxf(acc[ct][0] + bv.x, 0.f);
        float v1 = fmaxf(acc[ct][1] + bv.y, 0.f);
        float v2 = fmaxf(acc[ct][2] + bv.z, 0.f);
        float v3 = fmaxf(acc[ct][3] + bv.w, 0.f);
        if (RES) {
            uint2 rv = *(const uint2*)(hin + (size_t)cnode * HDIM + c0);
            v0 += bf2f((unsigned short)(rv.x & 0xFFFF));
            v1 += bf2f((unsigned short)(rv.x >> 16));
            v2 += bf2f((unsigned short)(rv.y & 0xFFFF));
            v3 += bf2f((unsigned short)(rv.y >> 16));
        }
        const int ch = 2 * ct + (q >> 1);
        unsigned short* p = &sAgg[lrow][((ch ^ (lrow & 7)) * 8) + (q & 1) * 4];
        unsigned int o0 = (unsigned int)f2bf(v0) | ((unsigned int)f2bf(v1) << 16);
        unsigned int o1 = (unsigned int)f2bf(v2) | ((unsigned int)f2bf(v3) << 16);
        uint2 o; o.x = o0; o.y = o1;
        *(uint2*)p = o;
    }

    const unsigned short* whp = Wh1b + (size_t)l16 * HDIM + q * 8;
    f32x4 hacc[4] = {};
#pragma unroll
    for (int k0 = 0; k0 < 128; k0 += 32) {
        const int ch = q + (k0 >> 3);
        short8 xf = *(const short8*)(&sAgg[lrow][(ch ^ (lrow & 7)) * 8]);
#pragma unroll
        for (int ct = 0; ct < 4; ++ct) {
            short8 wf = *(const short8*)(whp + (size_t)ct * 16 * HDIM + k0);
            hacc[ct] = __builtin_amdgcn_mfma_f32_16x16x32_bf16(wf, xf, hacc[ct], 0, 0, 0);
        }
    }

    const float bh2v = bh2[0];
    float p = 0.f;
#pragma unroll
    for (int ct = 0; ct < 4; ++ct) {
        const int c0 = ct * 16 + q * 4;
        float4 b1 = *(const float4*)(bh1 + c0);
        float4 w2 = *(const float4*)(Wh2 + c0);
        p += fmaxf(hacc[ct][0] + b1.x, 0.f) * w2.x;
        p += fmaxf(hacc[ct][1] + b1.y, 0.f) * w2.y;
        p += fmaxf(hacc[ct][2] + b1.z, 0.f) * w2.z;
        p += fmaxf(hacc[ct][3] + b1.w, 0.f) * w2.w;
    }
    p += __shfl_xor(p, 16, 64);
    p += __shfl_xor(p, 32, 64);
    if (q == 0 && node < n) scores[node] = p + bh2v;
}

// ---------------------------------------------------------------------------

extern "C" void kernel_launch(void* const* d_in, const int* in_sizes, int n_in,
                              void* d_out, int out_size, void* d_ws, size_t ws_size,
                              hipStream_t stream) {
    const int N = in_sizes[0];
    const int E = in_sizes[1] / 2;
    const int H = HDIM;

    const float* x    = (const float*)d_in[0];
    const int*   ei   = (const int*)d_in[1];
    const int*   src  = ei;
    const int*   dst  = ei + E;
    const float* Wenc = (const float*)d_in[2];
    const float* benc = (const float*)d_in[3];
    const float* demb = (const float*)d_in[4];
    const float* W1l  = (const float*)d_in[5];
    const float* b1l  = (const float*)d_in[6];
    const float* W1r  = (const float*)d_in[7];
    const float* W2l  = (const float*)d_in[8];
    const float* b2l  = (const float*)d_in[9];
    const float* W2r  = (const float*)d_in[10];
    const float* W3l  = (const float*)d_in[11];
    const float* b3l  = (const float*)d_in[12];
    const float* W3r  = (const float*)d_in[13];
    const float* Wh1  = (const float*)d_in[14];
    const float* bh1  = (const float*)d_in[15];
    const float* Wh2  = (const float*)d_in[16];
    const float* bh2  = (const float*)d_in[17];

    const int nbuk = (N + 127) >> 7;
    const int L    = 2 * nbuk * NB;
    const int nbk  = (L + SCH - 1) / SCH;
    const int ec   = (E + NB - 1) / NB;

    size_t off = 0;
    char* base = (char*)d_ws;
    auto carve = [&](size_t bytes) -> char* {
        char* p = base + off;
        off += (bytes + 255) & ~(size_t)255;
        return p;
    };
    unsigned short* bufA = (unsigned short*)carve((size_t)N * H * 2);
    unsigned short* bufB = (unsigned short*)carve((size_t)N * H * 2);
    unsigned short* csr  = (unsigned short*)carve((size_t)E * 2);
    int*   rowptr  = (int*)carve((size_t)(N + 1) * 4);
    int*   outdeg  = (int*)carve((size_t)N * 4);
    int*   bsum    = (int*)carve(4096);
    int*   hist    = (int*)carve((size_t)L * 4);
    int*   scanned = (int*)carve((size_t)L * 4);
    unsigned int*  binD = (unsigned int*)carve((size_t)E * 4);
    unsigned char* binS = (unsigned char*)carve((size_t)E);
    unsigned short* Wb  = (unsigned short*)carve((size_t)(6 * H * H + 64 * H) * 2);
    (void)ws_size; (void)n_in; (void)out_size;

    unsigned short* W1lb = Wb;
    unsigned short* W1rb = Wb + 1 * H * H;
    unsigned short* W2lb = Wb + 2 * H * H;
    unsigned short* W2rb = Wb + 3 * H * H;
    unsigned short* W3lb = Wb + 4 * H * H;
    unsigned short* W3rb = Wb + 5 * H * H;
    unsigned short* Wh1b = Wb + 6 * H * H;

    // 1) CSR build — LDS counting sort, no global atomics
    binhist_kernel<<<NB, 256, 0, stream>>>(src, dst, hist, E, nbuk, ec);
    hscan1_kernel<<<nbk, 256, 0, stream>>>(hist, bsum, L);
    hscan2_kernel<<<1, 64, 0, stream>>>(bsum, nbk);
    hscan3_kernel<<<nbk, 256, 0, stream>>>(hist, bsum, scanned, L);
    binscatter_kernel<<<NB, 256, 0, stream>>>(src, dst, scanned, binD, binS, E, nbuk, ec);
    finalize_kernel<<<nbuk, 256, 0, stream>>>(binD, binS, scanned, csr, rowptr, outdeg,
                                              E, N, nbuk);

    // 2) weights -> bf16 (row-major kept; includes Wh1)
    wconv_kernel<<<(6 * H * H + 64 * H) / 256, 256, 0, stream>>>(
        W1l, W1r, W2l, W2r, W3l, W3r, Wh1, Wb);

    // 3) encoder -> bufA (bf16)
    encoder_kernel<<<((size_t)N * 16 + 255) / 256, 256, 0, stream>>>(
        x, Wenc, benc, demb, outdeg, bufA, N);

    const int gF = (N + 127) / 128;

    // 4) layer 1: h1 = relu(sage(h))                        A -> B
    sage_fused<false, false><<<gF, 512, 0, stream>>>(bufA, rowptr, csr, W1lb, W1rb, b1l,
                                                     bufB, nullptr, nullptr, nullptr,
                                                     nullptr, nullptr, N);
    // 5) layer 2: h2 = relu(sage(h1)) + h1                  B -> A
    sage_fused<true, false><<<gF, 512, 0, stream>>>(bufB, rowptr, csr, W2lb, W2rb, b2l,
                                                    bufA, nullptr, nullptr, nullptr,
                                                    nullptr, nullptr, N);
    // 6) layer 3 + head: scores = head(relu(sage(h2))+h2)   A -> d_out
    sage_fused<true, true><<<gF, 512, 0, stream>>>(bufA, rowptr, csr, W3lb, W3rb, b3l,
                                                   nullptr, Wh1b, bh1, Wh2, bh2,
                                                   (float*)d_out, N);
}

// Round 9
// 225.540 us; speedup vs baseline: 1.1735x; 1.1735x over previous
//
#include <hip/hip_runtime.h>

// ---------------------------------------------------------------------------
// DCINet: 3-layer GraphSAGE (mean aggr) + degree embedding encoder + MLP head.
// N=50000, E=800000, H=128.
// R9: revert R8 fusion (gather lost 4x TLP in fused blocks — occupancy 26%).
//     R7 structure + 8-deep clamped-unroll gather in aggregate_kernel.
// ---------------------------------------------------------------------------

#define HDIM 128
#define NB 256          // binning blocks
#define MAXBUK 512      // max buckets (N <= 65536)
#define SCH 4096        // elements per scan block (256 thr x 16)

typedef __attribute__((ext_vector_type(8))) short short8;   // 8 bf16 (4 VGPR)
typedef __attribute__((ext_vector_type(4))) float f32x4;

__device__ inline float bf2f(unsigned short u) {
    union { unsigned int u; float f; } t; t.u = (unsigned int)u << 16; return t.f;
}
__device__ inline unsigned short f2bf(float f) {           // round-to-nearest-even
    union { float f; unsigned int u; } t; t.f = f;
    unsigned int u = t.u;
    return (unsigned short)((u + 0x7FFFu + ((u >> 16) & 1u)) >> 16);
}

// ---- phase 1: per-block LDS histograms over buckets (dst and src keys) -----

__global__ __launch_bounds__(256) void binhist_kernel(const int* __restrict__ src,
                                                      const int* __restrict__ dst,
                                                      int* __restrict__ hist,
                                                      int E, int nbuk, int ec) {
    __shared__ int hD[MAXBUK], hS[MAXBUK];
    const int tid = threadIdx.x, bid = blockIdx.x;
    for (int i = tid; i < nbuk; i += 256) { hD[i] = 0; hS[i] = 0; }
    __syncthreads();
    const int s0 = bid * ec, s1 = min(E, s0 + ec);
    for (int e = s0 + tid; e < s1; e += 256) {
        atomicAdd(&hD[dst[e] >> 7], 1);
        atomicAdd(&hS[src[e] >> 7], 1);
    }
    __syncthreads();
    for (int i = tid; i < nbuk; i += 256) {
        hist[(size_t)i * NB + bid] = hD[i];
        hist[(size_t)(nbuk + i) * NB + bid] = hS[i];
    }
}

// ---- phase 2: exclusive scan over hist[L], L = 2*nbuk*NB -------------------

__global__ __launch_bounds__(256) void hscan1_kernel(const int* __restrict__ a,
                                                     int* __restrict__ bsum, int L) {
    __shared__ int shw[4];
    const int tid = threadIdx.x;
    const int base = blockIdx.x * SCH + tid * 16;
    int s = 0;
#pragma unroll
    for (int j = 0; j < 16; ++j) { int i = base + j; if (i < L) s += a[i]; }
#pragma unroll
    for (int off = 32; off > 0; off >>= 1) s += __shfl_down(s, off, 64);
    if ((tid & 63) == 0) shw[tid >> 6] = s;
    __syncthreads();
    if (tid == 0) bsum[blockIdx.x] = shw[0] + shw[1] + shw[2] + shw[3];
}

__global__ void hscan2_kernel(int* __restrict__ bsum, int nb) {
    int lane = threadIdx.x;
    int v = (lane < nb) ? bsum[lane] : 0;
    int orig = v;
#pragma unroll
    for (int off = 1; off < 64; off <<= 1) {
        int t = __shfl_up(v, off, 64);
        if (lane >= off) v += t;
    }
    if (lane < nb) bsum[lane] = v - orig;      // exclusive
}

__global__ __launch_bounds__(256) void hscan3_kernel(const int* __restrict__ a,
                                                     const int* __restrict__ bsum,
                                                     int* __restrict__ out, int L) {
    __shared__ int shw[4];
    const int tid = threadIdx.x;
    const int lane = tid & 63;
    const int w = tid >> 6;
    const int base = blockIdx.x * SCH + tid * 16;
    int v[16];
    int s = 0;
#pragma unroll
    for (int j = 0; j < 16; ++j) {
        int i = base + j;
        v[j] = (i < L) ? a[i] : 0;
        s += v[j];
    }
    int incl = s;
#pragma unroll
    for (int off = 1; off < 64; off <<= 1) {
        int t = __shfl_up(incl, off, 64);
        if (lane >= off) incl += t;
    }
    if (lane == 63) shw[w] = incl;
    __syncthreads();
    int woff = 0;
#pragma unroll
    for (int j = 0; j < 4; ++j) if (j < w) woff += shw[j];
    int pfx = bsum[blockIdx.x] + woff + incl - s;
#pragma unroll
    for (int j = 0; j < 16; ++j) {
        int i = base + j;
        if (i < L) out[i] = pfx;
        pfx += v[j];
    }
}

// ---- phase 3: scatter edges into bucket-sorted arrays (LDS cursors) --------

__global__ __launch_bounds__(256) void binscatter_kernel(const int* __restrict__ src,
                                                         const int* __restrict__ dst,
                                                         const int* __restrict__ scanned,
                                                         unsigned int* __restrict__ binD,
                                                         unsigned char* __restrict__ binS,
                                                         int E, int nbuk, int ec) {
    __shared__ int curD[MAXBUK], curS[MAXBUK];
    const int tid = threadIdx.x, bid = blockIdx.x;
    for (int i = tid; i < nbuk; i += 256) {
        curD[i] = scanned[(size_t)i * NB + bid];
        curS[i] = scanned[(size_t)(nbuk + i) * NB + bid] - E;
    }
    __syncthreads();
    const int s0 = bid * ec, s1 = min(E, s0 + ec);
    for (int e = s0 + tid; e < s1; e += 256) {
        int s = src[e], d = dst[e];
        int pd = atomicAdd(&curD[d >> 7], 1);
        binD[pd] = (unsigned int)s | ((unsigned int)(d & 127) << 16);
        int ps = atomicAdd(&curS[s >> 7], 1);
        binS[ps] = (unsigned char)(s & 127);
    }
}

// ---- phase 4: per-bucket finalize -> rowptr, outdeg, u16 CSR ---------------

__global__ __launch_bounds__(256) void finalize_kernel(const unsigned int* __restrict__ binD,
                                                       const unsigned char* __restrict__ binS,
                                                       const int* __restrict__ scanned,
                                                       unsigned short* __restrict__ csr,
                                                       int* __restrict__ rowptr,
                                                       int* __restrict__ outdeg,
                                                       int E, int n, int nbuk) {
    __shared__ int cntD[128], cur[128], cntS[128];
    const int b = blockIdx.x, tid = threadIdx.x;
    if (tid < 128) { cntD[tid] = 0; cntS[tid] = 0; }
    __syncthreads();
    const int s0 = scanned[(size_t)b * NB];
    const int s1 = (b == nbuk - 1) ? E : scanned[(size_t)(b + 1) * NB];
    const int t0 = scanned[(size_t)(nbuk + b) * NB] - E;
    const int t1 = (b == nbuk - 1) ? E : scanned[(size_t)(nbuk + b + 1) * NB] - E;
    for (int e = s0 + tid; e < s1; e += 256) atomicAdd(&cntD[(binD[e] >> 16) & 127], 1);
    for (int e = t0 + tid; e < t1; e += 256) atomicAdd(&cntS[binS[e]], 1);
    __syncthreads();
    if (tid < 128) cur[tid] = cntD[tid];
    __syncthreads();
    for (int off = 1; off < 128; off <<= 1) {
        int t = (tid < 128 && tid >= off) ? cur[tid - off] : 0;
        __syncthreads();
        if (tid < 128) cur[tid] += t;
        __syncthreads();
    }
    if (tid < 128) {
        int ex = cur[tid] - cntD[tid];
        int node = b * 128 + tid;
        if (node < n) { rowptr[node] = s0 + ex; outdeg[node] = cntS[tid]; }
        cur[tid] = ex;
    }
    __syncthreads();
    for (int e = s0 + tid; e < s1; e += 256) {
        unsigned int p = binD[e];
        int pos = atomicAdd(&cur[(p >> 16) & 127], 1);
        csr[s0 + pos] = (unsigned short)(p & 0xFFFFu);
    }
    if (b == 0 && tid == 0) rowptr[n] = E;
}

// ---- weight fp32 -> bf16: 6x[128][128] + Wh1[64][128], row-major kept ------

__global__ void wconv_kernel(const float* __restrict__ W1l, const float* __restrict__ W1r,
                             const float* __restrict__ W2l, const float* __restrict__ W2r,
                             const float* __restrict__ W3l, const float* __restrict__ W3r,
                             const float* __restrict__ Wh1,
                             unsigned short* __restrict__ out) {
    int idx = blockIdx.x * 256 + threadIdx.x;
    const float* s;
    int o;
    if (idx < 98304) {
        int m = idx >> 14; o = idx & 16383;
        switch (m) {
            case 0: s = W1l; break; case 1: s = W1r; break;
            case 2: s = W2l; break; case 3: s = W2r; break;
            case 4: s = W3l; break; default: s = W3r; break;
        }
    } else {
        s = Wh1; o = idx - 98304;
    }
    out[idx] = f2bf(s[o]);
}

// ---- encoder: h = relu(x*Wenc + benc + deg_emb[min(outdeg,199)]) -> bf16 ---

__global__ void encoder_kernel(const float* __restrict__ x, const float* __restrict__ Wenc,
                               const float* __restrict__ benc, const float* __restrict__ demb,
                               const int* __restrict__ outdeg,
                               unsigned short* __restrict__ h, int n) {
    int idx = blockIdx.x * blockDim.x + threadIdx.x;   // over n*16
    if (idx >= n * 16) return;
    int i = idx >> 4, g = idx & 15;
    int d = outdeg[i]; if (d > 199) d = 199;
    float xv = x[i];
    const float* wp = Wenc + g * 8;
    const float* bp = benc + g * 8;
    const float* ep = demb + (size_t)d * HDIM + g * 8;
    short8 o;
#pragma unroll
    for (int j = 0; j < 8; ++j)
        o[j] = (short)f2bf(fmaxf(xv * wp[j] + bp[j] + ep[j], 0.f));
    *(short8*)(h + (size_t)i * HDIM + g * 8) = o;
}

// ---- mean aggregation: 4 nodes per wave (16 lanes each), 8-deep unroll -----

__global__ __launch_bounds__(256) void aggregate_kernel(const unsigned short* __restrict__ hin,
                                                        const int* __restrict__ row_ptr,
                                                        const unsigned short* __restrict__ csr,
                                                        unsigned short* __restrict__ agg, int n) {
    const int tid = threadIdx.x;
    const int i = blockIdx.x * 16 + (tid >> 4);
    if (i >= n) return;
    const int l16 = tid & 15;
    const int beg = row_ptr[i], end = row_ptr[i + 1];
    float a[8] = {};
    for (int e = beg; e < end; e += 8) {
        short8 v[8];
#pragma unroll
        for (int u = 0; u < 8; ++u) {                 // 8 loads in flight
            int ee = e + u; if (ee > end - 1) ee = end - 1;
            int sidx = csr[ee];
            v[u] = *(const short8*)(hin + (size_t)sidx * HDIM + l16 * 8);
        }
#pragma unroll
        for (int u = 0; u < 8; ++u) {
            if (e + u < end) {
#pragma unroll
                for (int k = 0; k < 8; ++k)
                    a[k] += bf2f((unsigned short)v[u][k]);
            }
        }
    }
    float inv = 1.f / fmaxf((float)(end - beg), 1.f);
    short8 o;
#pragma unroll
    for (int j = 0; j < 8; ++j) o[j] = (short)f2bf(a[j] * inv);
    *(short8*)(agg + (size_t)i * HDIM + l16 * 8) = o;
}

// ---- MFMA SAGE linear: out = relu(agg@Wl^T + hin@Wr^T + b) (+res), bf16 out
// Swapped operands: lane holds 4 consecutive out-cols per node -> packed 8B
// stores. Block = 4 waves; wave = 32 rows (2 node-groups of 16); K = 128.

template <bool RES>
__global__ __launch_bounds__(256) void gemm_mfma(const unsigned short* __restrict__ agg,
                                                 const unsigned short* __restrict__ hin,
                                                 const unsigned short* __restrict__ Wl,
                                                 const unsigned short* __restrict__ Wr,
                                                 const float* __restrict__ bias,
                                                 unsigned short* __restrict__ outBf, int n) {
    const int t = threadIdx.x;
    const int l = t & 63;
    const int wv = t >> 6;
    const int l16 = l & 15;
    const int q = l >> 4;                       // k-group / col-quad index 0..3
    const int row0 = blockIdx.x * 128 + wv * 32;
    const int node0 = min(row0 + l16, n - 1);
    const int node1 = min(row0 + 16 + l16, n - 1);

    const unsigned short* wlp = Wl + (size_t)l16 * HDIM + q * 8;
    const unsigned short* wrp = Wr + (size_t)l16 * HDIM + q * 8;
    const unsigned short* ap0 = agg + (size_t)node0 * HDIM + q * 8;
    const unsigned short* hp0 = hin + (size_t)node0 * HDIM + q * 8;
    const unsigned short* ap1 = agg + (size_t)node1 * HDIM + q * 8;
    const unsigned short* hp1 = hin + (size_t)node1 * HDIM + q * 8;

    f32x4 acc[2][8] = {};
#pragma unroll
    for (int k0 = 0; k0 < 128; k0 += 32) {
        short8 xa0 = *(const short8*)(ap0 + k0);
        short8 xh0 = *(const short8*)(hp0 + k0);
        short8 xa1 = *(const short8*)(ap1 + k0);
        short8 xh1 = *(const short8*)(hp1 + k0);
#pragma unroll
        for (int ct = 0; ct < 8; ++ct) {
            short8 bl = *(const short8*)(wlp + (size_t)ct * 16 * HDIM + k0);
            short8 br = *(const short8*)(wrp + (size_t)ct * 16 * HDIM + k0);
            acc[0][ct] = __builtin_amdgcn_mfma_f32_16x16x32_bf16(bl, xa0, acc[0][ct], 0, 0, 0);
            acc[0][ct] = __builtin_amdgcn_mfma_f32_16x16x32_bf16(br, xh0, acc[0][ct], 0, 0, 0);
            acc[1][ct] = __builtin_amdgcn_mfma_f32_16x16x32_bf16(bl, xa1, acc[1][ct], 0, 0, 0);
            acc[1][ct] = __builtin_amdgcn_mfma_f32_16x16x32_bf16(br, xh1, acc[1][ct], 0, 0, 0);
        }
    }

#pragma unroll
    for (int ng = 0; ng < 2; ++ng) {
        int node = row0 + ng * 16 + l16;
        if (node >= n) continue;
        int cnode = min(node, n - 1);
#pragma unroll
        for (int ct = 0; ct < 8; ++ct) {
            const int c0 = ct * 16 + q * 4;
            float4 bv = *(const float4*)(bias + c0);
            float v0 = fmaxf(acc[ng][ct][0] + bv.x, 0.f);
            float v1 = fmaxf(acc[ng][ct][1] + bv.y, 0.f);
            float v2 = fmaxf(acc[ng][ct][2] + bv.z, 0.f);
            float v3 = fmaxf(acc[ng][ct][3] + bv.w, 0.f);
            if (RES) {
                const unsigned short* rp = hin + (size_t)cnode * HDIM + c0;
                uint2 rv = *(const uint2*)rp;
                v0 += bf2f((unsigned short)(rv.x & 0xFFFF));
                v1 += bf2f((unsigned short)(rv.x >> 16));
                v2 += bf2f((unsigned short)(rv.y & 0xFFFF));
                v3 += bf2f((unsigned short)(rv.y >> 16));
            }
            unsigned int o0 = (unsigned int)f2bf(v0) | ((unsigned int)f2bf(v1) << 16);
            unsigned int o1 = (unsigned int)f2bf(v2) | ((unsigned int)f2bf(v3) << 16);
            uint2 o; o.x = o0; o.y = o1;
            *(uint2*)(outBf + (size_t)node * HDIM + c0) = o;
        }
    }
}

// ---- MFMA head: scores = relu(h3@Wh1^T + bh1) @ Wh2 + bh2 ------------------

__global__ __launch_bounds__(256) void head_mfma(const unsigned short* __restrict__ h3,
                                                 const unsigned short* __restrict__ Wh1b,
                                                 const float* __restrict__ bh1,
                                                 const float* __restrict__ Wh2,
                                                 const float* __restrict__ bh2,
                                                 float* __restrict__ scores, int n) {
    const int t = threadIdx.x;
    const int l = t & 63;
    const int wv = t >> 6;
    const int l16 = l & 15;
    const int q = l >> 4;
    const int row0 = blockIdx.x * 256 + wv * 64;

    const unsigned short* whp = Wh1b + (size_t)l16 * HDIM + q * 8;

    f32x4 acc[4][4] = {};
#pragma unroll
    for (int k0 = 0; k0 < 128; k0 += 32) {
        short8 xf[4];
#pragma unroll
        for (int ng = 0; ng < 4; ++ng) {
            int node = min(row0 + ng * 16 + l16, n - 1);
            xf[ng] = *(const short8*)(h3 + (size_t)node * HDIM + q * 8 + k0);
        }
#pragma unroll
        for (int ct = 0; ct < 4; ++ct) {
            short8 wf = *(const short8*)(whp + (size_t)ct * 16 * HDIM + k0);
#pragma unroll
            for (int ng = 0; ng < 4; ++ng)
                acc[ng][ct] = __builtin_amdgcn_mfma_f32_16x16x32_bf16(wf, xf[ng], acc[ng][ct], 0, 0, 0);
        }
    }

    const float bh2v = bh2[0];
#pragma unroll
    for (int ng = 0; ng < 4; ++ng) {
        float p = 0.f;
#pragma unroll
        for (int ct = 0; ct < 4; ++ct) {
            const int c0 = ct * 16 + q * 4;
            float4 b1 = *(const float4*)(bh1 + c0);
            float4 w2 = *(const float4*)(Wh2 + c0);
            p += fmaxf(acc[ng][ct][0] + b1.x, 0.f) * w2.x;
            p += fmaxf(acc[ng][ct][1] + b1.y, 0.f) * w2.y;
            p += fmaxf(acc[ng][ct][2] + b1.z, 0.f) * w2.z;
            p += fmaxf(acc[ng][ct][3] + b1.w, 0.f) * w2.w;
        }
        p += __shfl_xor(p, 16, 64);
        p += __shfl_xor(p, 32, 64);
        int node = row0 + ng * 16 + l16;
        if (q == 0 && node < n) scores[node] = p + bh2v;
    }
}

// ---------------------------------------------------------------------------

extern "C" void kernel_launch(void* const* d_in, const int* in_sizes, int n_in,
                              void* d_out, int out_size, void* d_ws, size_t ws_size,
                              hipStream_t stream) {
    const int N = in_sizes[0];
    const int E = in_sizes[1] / 2;
    const int H = HDIM;

    const float* x    = (const float*)d_in[0];
    const int*   ei   = (const int*)d_in[1];
    const int*   src  = ei;
    const int*   dst  = ei + E;
    const float* Wenc = (const float*)d_in[2];
    const float* benc = (const float*)d_in[3];
    const float* demb = (const float*)d_in[4];
    const float* W1l  = (const float*)d_in[5];
    const float* b1l  = (const float*)d_in[6];
    const float* W1r  = (const float*)d_in[7];
    const float* W2l  = (const float*)d_in[8];
    const float* b2l  = (const float*)d_in[9];
    const float* W2r  = (const float*)d_in[10];
    const float* W3l  = (const float*)d_in[11];
    const float* b3l  = (const float*)d_in[12];
    const float* W3r  = (const float*)d_in[13];
    const float* Wh1  = (const float*)d_in[14];
    const float* bh1  = (const float*)d_in[15];
    const float* Wh2  = (const float*)d_in[16];
    const float* bh2  = (const float*)d_in[17];

    const int nbuk = (N + 127) >> 7;
    const int L    = 2 * nbuk * NB;
    const int nbk  = (L + SCH - 1) / SCH;
    const int ec   = (E + NB - 1) / NB;

    size_t off = 0;
    char* base = (char*)d_ws;
    auto carve = [&](size_t bytes) -> char* {
        char* p = base + off;
        off += (bytes + 255) & ~(size_t)255;
        return p;
    };
    unsigned short* bufA = (unsigned short*)carve((size_t)N * H * 2);
    unsigned short* bufB = (unsigned short*)carve((size_t)N * H * 2);
    unsigned short* bufC = (unsigned short*)carve((size_t)N * H * 2);
    unsigned short* csr  = (unsigned short*)carve((size_t)E * 2);
    int*   rowptr  = (int*)carve((size_t)(N + 1) * 4);
    int*   outdeg  = (int*)carve((size_t)N * 4);
    int*   bsum    = (int*)carve(4096);
    int*   hist    = (int*)carve((size_t)L * 4);
    int*   scanned = (int*)carve((size_t)L * 4);
    unsigned int*  binD = (unsigned int*)carve((size_t)E * 4);
    unsigned char* binS = (unsigned char*)carve((size_t)E);
    unsigned short* Wb  = (unsigned short*)carve((size_t)(6 * H * H + 64 * H) * 2);
    (void)ws_size; (void)n_in; (void)out_size;

    unsigned short* W1lb = Wb;
    unsigned short* W1rb = Wb + 1 * H * H;
    unsigned short* W2lb = Wb + 2 * H * H;
    unsigned short* W2rb = Wb + 3 * H * H;
    unsigned short* W3lb = Wb + 4 * H * H;
    unsigned short* W3rb = Wb + 5 * H * H;
    unsigned short* Wh1b = Wb + 6 * H * H;

    // 1) CSR build — LDS counting sort, no global atomics
    binhist_kernel<<<NB, 256, 0, stream>>>(src, dst, hist, E, nbuk, ec);
    hscan1_kernel<<<nbk, 256, 0, stream>>>(hist, bsum, L);
    hscan2_kernel<<<1, 64, 0, stream>>>(bsum, nbk);
    hscan3_kernel<<<nbk, 256, 0, stream>>>(hist, bsum, scanned, L);
    binscatter_kernel<<<NB, 256, 0, stream>>>(src, dst, scanned, binD, binS, E, nbuk, ec);
    finalize_kernel<<<nbuk, 256, 0, stream>>>(binD, binS, scanned, csr, rowptr, outdeg,
                                              E, N, nbuk);

    // 2) weights -> bf16 (row-major kept; includes Wh1)
    wconv_kernel<<<(6 * H * H + 64 * H) / 256, 256, 0, stream>>>(
        W1l, W1r, W2l, W2r, W3l, W3r, Wh1, Wb);

    // 3) encoder -> bufA (bf16)
    encoder_kernel<<<((size_t)N * 16 + 255) / 256, 256, 0, stream>>>(
        x, Wenc, benc, demb, outdeg, bufA, N);

    const int gAgg  = (N + 15) / 16;
    const int gGemm = (N + 127) / 128;
    const int gHead = (N + 255) / 256;

    // 4) layer 1: h1 = relu(sage(h))            A -> B -> C
    aggregate_kernel<<<gAgg, 256, 0, stream>>>(bufA, rowptr, csr, bufB, N);
    gemm_mfma<false><<<gGemm, 256, 0, stream>>>(bufB, bufA, W1lb, W1rb, b1l, bufC, N);

    // 5) layer 2: h2 = relu(sage(h1)) + h1      C -> B -> A
    aggregate_kernel<<<gAgg, 256, 0, stream>>>(bufC, rowptr, csr, bufB, N);
    gemm_mfma<true><<<gGemm, 256, 0, stream>>>(bufB, bufC, W2lb, W2rb, b2l, bufA, N);

    // 6) layer 3: h3 = relu(sage(h2)) + h2      A -> B -> C
    aggregate_kernel<<<gAgg, 256, 0, stream>>>(bufA, rowptr, csr, bufB, N);
    gemm_mfma<true><<<gGemm, 256, 0, stream>>>(bufB, bufA, W3lb, W3rb, b3l, bufC, N);

    // 7) head: scores = relu(h3@Wh1^T+bh1)@Wh2 + bh2   C -> d_out
    head_mfma<<<gHead, 256, 0, stream>>>(bufC, Wh1b, bh1, Wh2, bh2, (float*)d_out, N);
}

// Round 10
// 187.741 us; speedup vs baseline: 1.4097x; 1.2013x over previous
//
#include <hip/hip_runtime.h>

// ---------------------------------------------------------------------------
// DCINet: 3-layer GraphSAGE (mean aggr) + degree embedding encoder + MLP head.
// N=50000, E=800000, H=128.
// R10: gemm_mfma stages Wl+Wr in LDS (64KB, XOR-swizzled chunks) — kills the
//      100MB/gemm redundant weight re-read from L2. hscan2 folded into hscan3
//      (per-block shfl reduce over chunk sums). Rest as R9.
// ---------------------------------------------------------------------------

#define HDIM 128
#define NB 256          // binning blocks
#define MAXBUK 512      // max buckets (N <= 65536)
#define SCH 4096        // elements per scan block (256 thr x 16)

typedef __attribute__((ext_vector_type(8))) short short8;   // 8 bf16 (4 VGPR)
typedef __attribute__((ext_vector_type(4))) float f32x4;

__device__ inline float bf2f(unsigned short u) {
    union { unsigned int u; float f; } t; t.u = (unsigned int)u << 16; return t.f;
}
__device__ inline unsigned short f2bf(float f) {           // round-to-nearest-even
    union { float f; unsigned int u; } t; t.f = f;
    unsigned int u = t.u;
    return (unsigned short)((u + 0x7FFFu + ((u >> 16) & 1u)) >> 16);
}

// ---- phase 1: per-block LDS histograms over buckets (dst and src keys) -----

__global__ __launch_bounds__(256) void binhist_kernel(const int* __restrict__ src,
                                                      const int* __restrict__ dst,
                                                      int* __restrict__ hist,
                                                      int E, int nbuk, int ec) {
    __shared__ int hD[MAXBUK], hS[MAXBUK];
    const int tid = threadIdx.x, bid = blockIdx.x;
    for (int i = tid; i < nbuk; i += 256) { hD[i] = 0; hS[i] = 0; }
    __syncthreads();
    const int s0 = bid * ec, s1 = min(E, s0 + ec);
    for (int e = s0 + tid; e < s1; e += 256) {
        atomicAdd(&hD[dst[e] >> 7], 1);
        atomicAdd(&hS[src[e] >> 7], 1);
    }
    __syncthreads();
    for (int i = tid; i < nbuk; i += 256) {
        hist[(size_t)i * NB + bid] = hD[i];
        hist[(size_t)(nbuk + i) * NB + bid] = hS[i];
    }
}

// ---- phase 2: chunk sums, then scan fused into hscan3 ----------------------

__global__ __launch_bounds__(256) void hscan1_kernel(const int* __restrict__ a,
                                                     int* __restrict__ bsum, int L) {
    __shared__ int shw[4];
    const int tid = threadIdx.x;
    const int base = blockIdx.x * SCH + tid * 16;
    int s = 0;
#pragma unroll
    for (int j = 0; j < 16; ++j) { int i = base + j; if (i < L) s += a[i]; }
#pragma unroll
    for (int off = 32; off > 0; off >>= 1) s += __shfl_down(s, off, 64);
    if ((tid & 63) == 0) shw[tid >> 6] = s;
    __syncthreads();
    if (tid == 0) bsum[blockIdx.x] = shw[0] + shw[1] + shw[2] + shw[3];
}

// per-chunk exclusive scan; block base computed in-kernel from bsum (nbk<=64)
__global__ __launch_bounds__(256) void hscan3_kernel(const int* __restrict__ a,
                                                     const int* __restrict__ bsum,
                                                     int* __restrict__ out, int L) {
    __shared__ int shw[4];
    __shared__ int sBase;
    const int tid = threadIdx.x;
    const int lane = tid & 63;
    const int w = tid >> 6;
    if (tid < 64) {                      // wave 0: base = sum of preceding chunks
        int v = (lane < blockIdx.x) ? bsum[lane] : 0;
#pragma unroll
        for (int off = 32; off > 0; off >>= 1) v += __shfl_down(v, off, 64);
        if (lane == 0) sBase = v;
    }
    const int base = blockIdx.x * SCH + tid * 16;
    int v[16];
    int s = 0;
#pragma unroll
    for (int j = 0; j < 16; ++j) {
        int i = base + j;
        v[j] = (i < L) ? a[i] : 0;
        s += v[j];
    }
    int incl = s;
#pragma unroll
    for (int off = 1; off < 64; off <<= 1) {
        int t = __shfl_up(incl, off, 64);
        if (lane >= off) incl += t;
    }
    if (lane == 63) shw[w] = incl;
    __syncthreads();
    int woff = 0;
#pragma unroll
    for (int j = 0; j < 4; ++j) if (j < w) woff += shw[j];
    int pfx = sBase + woff + incl - s;
#pragma unroll
    for (int j = 0; j < 16; ++j) {
        int i = base + j;
        if (i < L) out[i] = pfx;
        pfx += v[j];
    }
}

// ---- phase 3: scatter edges into bucket-sorted arrays (LDS cursors) --------

__global__ __launch_bounds__(256) void binscatter_kernel(const int* __restrict__ src,
                                                         const int* __restrict__ dst,
                                                         const int* __restrict__ scanned,
                                                         unsigned int* __restrict__ binD,
                                                         unsigned char* __restrict__ binS,
                                                         int E, int nbuk, int ec) {
    __shared__ int curD[MAXBUK], curS[MAXBUK];
    const int tid = threadIdx.x, bid = blockIdx.x;
    for (int i = tid; i < nbuk; i += 256) {
        curD[i] = scanned[(size_t)i * NB + bid];
        curS[i] = scanned[(size_t)(nbuk + i) * NB + bid] - E;
    }
    __syncthreads();
    const int s0 = bid * ec, s1 = min(E, s0 + ec);
    for (int e = s0 + tid; e < s1; e += 256) {
        int s = src[e], d = dst[e];
        int pd = atomicAdd(&curD[d >> 7], 1);
        binD[pd] = (unsigned int)s | ((unsigned int)(d & 127) << 16);
        int ps = atomicAdd(&curS[s >> 7], 1);
        binS[ps] = (unsigned char)(s & 127);
    }
}

// ---- phase 4: per-bucket finalize -> rowptr, outdeg, u16 CSR ---------------

__global__ __launch_bounds__(256) void finalize_kernel(const unsigned int* __restrict__ binD,
                                                       const unsigned char* __restrict__ binS,
                                                       const int* __restrict__ scanned,
                                                       unsigned short* __restrict__ csr,
                                                       int* __restrict__ rowptr,
                                                       int* __restrict__ outdeg,
                                                       int E, int n, int nbuk) {
    __shared__ int cntD[128], cur[128], cntS[128];
    const int b = blockIdx.x, tid = threadIdx.x;
    if (tid < 128) { cntD[tid] = 0; cntS[tid] = 0; }
    __syncthreads();
    const int s0 = scanned[(size_t)b * NB];
    const int s1 = (b == nbuk - 1) ? E : scanned[(size_t)(b + 1) * NB];
    const int t0 = scanned[(size_t)(nbuk + b) * NB] - E;
    const int t1 = (b == nbuk - 1) ? E : scanned[(size_t)(nbuk + b + 1) * NB] - E;
    for (int e = s0 + tid; e < s1; e += 256) atomicAdd(&cntD[(binD[e] >> 16) & 127], 1);
    for (int e = t0 + tid; e < t1; e += 256) atomicAdd(&cntS[binS[e]], 1);
    __syncthreads();
    if (tid < 128) cur[tid] = cntD[tid];
    __syncthreads();
    for (int off = 1; off < 128; off <<= 1) {
        int t = (tid < 128 && tid >= off) ? cur[tid - off] : 0;
        __syncthreads();
        if (tid < 128) cur[tid] += t;
        __syncthreads();
    }
    if (tid < 128) {
        int ex = cur[tid] - cntD[tid];
        int node = b * 128 + tid;
        if (node < n) { rowptr[node] = s0 + ex; outdeg[node] = cntS[tid]; }
        cur[tid] = ex;
    }
    __syncthreads();
    for (int e = s0 + tid; e < s1; e += 256) {
        unsigned int p = binD[e];
        int pos = atomicAdd(&cur[(p >> 16) & 127], 1);
        csr[s0 + pos] = (unsigned short)(p & 0xFFFFu);
    }
    if (b == 0 && tid == 0) rowptr[n] = E;
}

// ---- weight fp32 -> bf16: 6x[128][128] + Wh1[64][128], row-major kept ------

__global__ void wconv_kernel(const float* __restrict__ W1l, const float* __restrict__ W1r,
                             const float* __restrict__ W2l, const float* __restrict__ W2r,
                             const float* __restrict__ W3l, const float* __restrict__ W3r,
                             const float* __restrict__ Wh1,
                             unsigned short* __restrict__ out) {
    int idx = blockIdx.x * 256 + threadIdx.x;
    const float* s;
    int o;
    if (idx < 98304) {
        int m = idx >> 14; o = idx & 16383;
        switch (m) {
            case 0: s = W1l; break; case 1: s = W1r; break;
            case 2: s = W2l; break; case 3: s = W2r; break;
            case 4: s = W3l; break; default: s = W3r; break;
        }
    } else {
        s = Wh1; o = idx - 98304;
    }
    out[idx] = f2bf(s[o]);
}

// ---- encoder: h = relu(x*Wenc + benc + deg_emb[min(outdeg,199)]) -> bf16 ---

__global__ void encoder_kernel(const float* __restrict__ x, const float* __restrict__ Wenc,
                               const float* __restrict__ benc, const float* __restrict__ demb,
                               const int* __restrict__ outdeg,
                               unsigned short* __restrict__ h, int n) {
    int idx = blockIdx.x * blockDim.x + threadIdx.x;   // over n*16
    if (idx >= n * 16) return;
    int i = idx >> 4, g = idx & 15;
    int d = outdeg[i]; if (d > 199) d = 199;
    float xv = x[i];
    const float* wp = Wenc + g * 8;
    const float* bp = benc + g * 8;
    const float* ep = demb + (size_t)d * HDIM + g * 8;
    short8 o;
#pragma unroll
    for (int j = 0; j < 8; ++j)
        o[j] = (short)f2bf(fmaxf(xv * wp[j] + bp[j] + ep[j], 0.f));
    *(short8*)(h + (size_t)i * HDIM + g * 8) = o;
}

// ---- mean aggregation: 4 nodes per wave (16 lanes each), 8-deep unroll -----

__global__ __launch_bounds__(256) void aggregate_kernel(const unsigned short* __restrict__ hin,
                                                        const int* __restrict__ row_ptr,
                                                        const unsigned short* __restrict__ csr,
                                                        unsigned short* __restrict__ agg, int n) {
    const int tid = threadIdx.x;
    const int i = blockIdx.x * 16 + (tid >> 4);
    if (i >= n) return;
    const int l16 = tid & 15;
    const int beg = row_ptr[i], end = row_ptr[i + 1];
    float a[8] = {};
    for (int e = beg; e < end; e += 8) {
        short8 v[8];
#pragma unroll
        for (int u = 0; u < 8; ++u) {                 // 8 loads in flight
            int ee = e + u; if (ee > end - 1) ee = end - 1;
            int sidx = csr[ee];
            v[u] = *(const short8*)(hin + (size_t)sidx * HDIM + l16 * 8);
        }
#pragma unroll
        for (int u = 0; u < 8; ++u) {
            if (e + u < end) {
#pragma unroll
                for (int k = 0; k < 8; ++k)
                    a[k] += bf2f((unsigned short)v[u][k]);
            }
        }
    }
    float inv = 1.f / fmaxf((float)(end - beg), 1.f);
    short8 o;
#pragma unroll
    for (int j = 0; j < 8; ++j) o[j] = (short)f2bf(a[j] * inv);
    *(short8*)(agg + (size_t)i * HDIM + l16 * 8) = o;
}

// ---- MFMA SAGE linear: out = relu(agg@Wl^T + hin@Wr^T + b) (+res), bf16 out
// Swapped operands; weights staged in LDS once per block (XOR-swizzled chunks,
// 2-way bank alias = free). Block = 4 waves; wave = 32 rows; K = 128.

template <bool RES>
__global__ __launch_bounds__(256) void gemm_mfma(const unsigned short* __restrict__ agg,
                                                 const unsigned short* __restrict__ hin,
                                                 const unsigned short* __restrict__ Wl,
                                                 const unsigned short* __restrict__ Wr,
                                                 const float* __restrict__ bias,
                                                 unsigned short* __restrict__ outBf, int n) {
    __shared__ unsigned short sWl[128][128];
    __shared__ unsigned short sWr[128][128];
    const int t = threadIdx.x;

    // stage weights: 2048 chunks of 8 bf16 each matrix; swizzle chunk ^= row&7
    for (int i = t; i < 2048; i += 256) {
        int r = i >> 4, cc = i & 15;
        int sc = (cc ^ (r & 7)) * 8;
        *(short8*)(&sWl[r][sc]) = *(const short8*)(Wl + (size_t)r * HDIM + cc * 8);
        *(short8*)(&sWr[r][sc]) = *(const short8*)(Wr + (size_t)r * HDIM + cc * 8);
    }
    __syncthreads();

    const int l = t & 63;
    const int wv = t >> 6;
    const int l16 = l & 15;
    const int q = l >> 4;                       // k-group / col-quad index 0..3
    const int swz = l16 & 7;
    const int row0 = blockIdx.x * 128 + wv * 32;
    const int node0 = min(row0 + l16, n - 1);
    const int node1 = min(row0 + 16 + l16, n - 1);

    const unsigned short* ap0 = agg + (size_t)node0 * HDIM + q * 8;
    const unsigned short* hp0 = hin + (size_t)node0 * HDIM + q * 8;
    const unsigned short* ap1 = agg + (size_t)node1 * HDIM + q * 8;
    const unsigned short* hp1 = hin + (size_t)node1 * HDIM + q * 8;

    f32x4 acc[2][8] = {};
#pragma unroll
    for (int k0 = 0; k0 < 128; k0 += 32) {
        short8 xa0 = *(const short8*)(ap0 + k0);
        short8 xh0 = *(const short8*)(hp0 + k0);
        short8 xa1 = *(const short8*)(ap1 + k0);
        short8 xh1 = *(const short8*)(hp1 + k0);
        const int ch = q + (k0 >> 3);
        const int sc = (ch ^ swz) * 8;
#pragma unroll
        for (int ct = 0; ct < 8; ++ct) {
            short8 bl = *(const short8*)(&sWl[ct * 16 + l16][sc]);
            short8 br = *(const short8*)(&sWr[ct * 16 + l16][sc]);
            acc[0][ct] = __builtin_amdgcn_mfma_f32_16x16x32_bf16(bl, xa0, acc[0][ct], 0, 0, 0);
            acc[0][ct] = __builtin_amdgcn_mfma_f32_16x16x32_bf16(br, xh0, acc[0][ct], 0, 0, 0);
            acc[1][ct] = __builtin_amdgcn_mfma_f32_16x16x32_bf16(bl, xa1, acc[1][ct], 0, 0, 0);
            acc[1][ct] = __builtin_amdgcn_mfma_f32_16x16x32_bf16(br, xh1, acc[1][ct], 0, 0, 0);
        }
    }

#pragma unroll
    for (int ng = 0; ng < 2; ++ng) {
        int node = row0 + ng * 16 + l16;
        if (node >= n) continue;
        int cnode = min(node, n - 1);
#pragma unroll
        for (int ct = 0; ct < 8; ++ct) {
            const int c0 = ct * 16 + q * 4;
            float4 bv = *(const float4*)(bias + c0);
            float v0 = fmaxf(acc[ng][ct][0] + bv.x, 0.f);
            float v1 = fmaxf(acc[ng][ct][1] + bv.y, 0.f);
            float v2 = fmaxf(acc[ng][ct][2] + bv.z, 0.f);
            float v3 = fmaxf(acc[ng][ct][3] + bv.w, 0.f);
            if (RES) {
                const unsigned short* rp = hin + (size_t)cnode * HDIM + c0;
                uint2 rv = *(const uint2*)rp;
                v0 += bf2f((unsigned short)(rv.x & 0xFFFF));
                v1 += bf2f((unsigned short)(rv.x >> 16));
                v2 += bf2f((unsigned short)(rv.y & 0xFFFF));
                v3 += bf2f((unsigned short)(rv.y >> 16));
            }
            unsigned int o0 = (unsigned int)f2bf(v0) | ((unsigned int)f2bf(v1) << 16);
            unsigned int o1 = (unsigned int)f2bf(v2) | ((unsigned int)f2bf(v3) << 16);
            uint2 o; o.x = o0; o.y = o1;
            *(uint2*)(outBf + (size_t)node * HDIM + c0) = o;
        }
    }
}

// ---- MFMA head: scores = relu(h3@Wh1^T + bh1) @ Wh2 + bh2 ------------------

__global__ __launch_bounds__(256) void head_mfma(const unsigned short* __restrict__ h3,
                                                 const unsigned short* __restrict__ Wh1b,
                                                 const float* __restrict__ bh1,
                                                 const float* __restrict__ Wh2,
                                                 const float* __restrict__ bh2,
                                                 float* __restrict__ scores, int n) {
    const int t = threadIdx.x;
    const int l = t & 63;
    const int wv = t >> 6;
    const int l16 = l & 15;
    const int q = l >> 4;
    const int row0 = blockIdx.x * 256 + wv * 64;

    const unsigned short* whp = Wh1b + (size_t)l16 * HDIM + q * 8;

    f32x4 acc[4][4] = {};
#pragma unroll
    for (int k0 = 0; k0 < 128; k0 += 32) {
        short8 xf[4];
#pragma unroll
        for (int ng = 0; ng < 4; ++ng) {
            int node = min(row0 + ng * 16 + l16, n - 1);
            xf[ng] = *(const short8*)(h3 + (size_t)node * HDIM + q * 8 + k0);
        }
#pragma unroll
        for (int ct = 0; ct < 4; ++ct) {
            short8 wf = *(const short8*)(whp + (size_t)ct * 16 * HDIM + k0);
#pragma unroll
            for (int ng = 0; ng < 4; ++ng)
                acc[ng][ct] = __builtin_amdgcn_mfma_f32_16x16x32_bf16(wf, xf[ng], acc[ng][ct], 0, 0, 0);
        }
    }

    const float bh2v = bh2[0];
#pragma unroll
    for (int ng = 0; ng < 4; ++ng) {
        float p = 0.f;
#pragma unroll
        for (int ct = 0; ct < 4; ++ct) {
            const int c0 = ct * 16 + q * 4;
            float4 b1 = *(const float4*)(bh1 + c0);
            float4 w2 = *(const float4*)(Wh2 + c0);
            p += fmaxf(acc[ng][ct][0] + b1.x, 0.f) * w2.x;
            p += fmaxf(acc[ng][ct][1] + b1.y, 0.f) * w2.y;
            p += fmaxf(acc[ng][ct][2] + b1.z, 0.f) * w2.z;
            p += fmaxf(acc[ng][ct][3] + b1.w, 0.f) * w2.w;
        }
        p += __shfl_xor(p, 16, 64);
        p += __shfl_xor(p, 32, 64);
        int node = row0 + ng * 16 + l16;
        if (q == 0 && node < n) scores[node] = p + bh2v;
    }
}

// ---------------------------------------------------------------------------

extern "C" void kernel_launch(void* const* d_in, const int* in_sizes, int n_in,
                              void* d_out, int out_size, void* d_ws, size_t ws_size,
                              hipStream_t stream) {
    const int N = in_sizes[0];
    const int E = in_sizes[1] / 2;
    const int H = HDIM;

    const float* x    = (const float*)d_in[0];
    const int*   ei   = (const int*)d_in[1];
    const int*   src  = ei;
    const int*   dst  = ei + E;
    const float* Wenc = (const float*)d_in[2];
    const float* benc = (const float*)d_in[3];
    const float* demb = (const float*)d_in[4];
    const float* W1l  = (const float*)d_in[5];
    const float* b1l  = (const float*)d_in[6];
    const float* W1r  = (const float*)d_in[7];
    const float* W2l  = (const float*)d_in[8];
    const float* b2l  = (const float*)d_in[9];
    const float* W2r  = (const float*)d_in[10];
    const float* W3l  = (const float*)d_in[11];
    const float* b3l  = (const float*)d_in[12];
    const float* W3r  = (const float*)d_in[13];
    const float* Wh1  = (const float*)d_in[14];
    const float* bh1  = (const float*)d_in[15];
    const float* Wh2  = (const float*)d_in[16];
    const float* bh2  = (const float*)d_in[17];

    const int nbuk = (N + 127) >> 7;
    const int L    = 2 * nbuk * NB;
    const int nbk  = (L + SCH - 1) / SCH;
    const int ec   = (E + NB - 1) / NB;

    size_t off = 0;
    char* base = (char*)d_ws;
    auto carve = [&](size_t bytes) -> char* {
        char* p = base + off;
        off += (bytes + 255) & ~(size_t)255;
        return p;
    };
    unsigned short* bufA = (unsigned short*)carve((size_t)N * H * 2);
    unsigned short* bufB = (unsigned short*)carve((size_t)N * H * 2);
    unsigned short* bufC = (unsigned short*)carve((size_t)N * H * 2);
    unsigned short* csr  = (unsigned short*)carve((size_t)E * 2);
    int*   rowptr  = (int*)carve((size_t)(N + 1) * 4);
    int*   outdeg  = (int*)carve((size_t)N * 4);
    int*   bsum    = (int*)carve(4096);
    int*   hist    = (int*)carve((size_t)L * 4);
    int*   scanned = (int*)carve((size_t)L * 4);
    unsigned int*  binD = (unsigned int*)carve((size_t)E * 4);
    unsigned char* binS = (unsigned char*)carve((size_t)E);
    unsigned short* Wb  = (unsigned short*)carve((size_t)(6 * H * H + 64 * H) * 2);
    (void)ws_size; (void)n_in; (void)out_size;

    unsigned short* W1lb = Wb;
    unsigned short* W1rb = Wb + 1 * H * H;
    unsigned short* W2lb = Wb + 2 * H * H;
    unsigned short* W2rb = Wb + 3 * H * H;
    unsigned short* W3lb = Wb + 4 * H * H;
    unsigned short* W3rb = Wb + 5 * H * H;
    unsigned short* Wh1b = Wb + 6 * H * H;

    // 1) CSR build — LDS counting sort, no global atomics
    binhist_kernel<<<NB, 256, 0, stream>>>(src, dst, hist, E, nbuk, ec);
    hscan1_kernel<<<nbk, 256, 0, stream>>>(hist, bsum, L);
    hscan3_kernel<<<nbk, 256, 0, stream>>>(hist, bsum, scanned, L);
    binscatter_kernel<<<NB, 256, 0, stream>>>(src, dst, scanned, binD, binS, E, nbuk, ec);
    finalize_kernel<<<nbuk, 256, 0, stream>>>(binD, binS, scanned, csr, rowptr, outdeg,
                                              E, N, nbuk);

    // 2) weights -> bf16 (row-major kept; includes Wh1)
    wconv_kernel<<<(6 * H * H + 64 * H) / 256, 256, 0, stream>>>(
        W1l, W1r, W2l, W2r, W3l, W3r, Wh1, Wb);

    // 3) encoder -> bufA (bf16)
    encoder_kernel<<<((size_t)N * 16 + 255) / 256, 256, 0, stream>>>(
        x, Wenc, benc, demb, outdeg, bufA, N);

    const int gAgg  = (N + 15) / 16;
    const int gGemm = (N + 127) / 128;
    const int gHead = (N + 255) / 256;

    // 4) layer 1: h1 = relu(sage(h))            A -> B -> C
    aggregate_kernel<<<gAgg, 256, 0, stream>>>(bufA, rowptr, csr, bufB, N);
    gemm_mfma<false><<<gGemm, 256, 0, stream>>>(bufB, bufA, W1lb, W1rb, b1l, bufC, N);

    // 5) layer 2: h2 = relu(sage(h1)) + h1      C -> B -> A
    aggregate_kernel<<<gAgg, 256, 0, stream>>>(bufC, rowptr, csr, bufB, N);
    gemm_mfma<true><<<gGemm, 256, 0, stream>>>(bufB, bufC, W2lb, W2rb, b2l, bufA, N);

    // 6) layer 3: h3 = relu(sage(h2)) + h2      A -> B -> C
    aggregate_kernel<<<gAgg, 256, 0, stream>>>(bufA, rowptr, csr, bufB, N);
    gemm_mfma<true><<<gGemm, 256, 0, stream>>>(bufB, bufA, W3lb, W3rb, b3l, bufC, N);

    // 7) head: scores = relu(h3@Wh1^T+bh1)@Wh2 + bh2   C -> d_out
    head_mfma<<<gHead, 256, 0, stream>>>(bufC, Wh1b, bh1, Wh2, bh2, (float*)d_out, N);
}

// Round 11
// 187.236 us; speedup vs baseline: 1.4135x; 1.0027x over previous
//
#include <hip/hip_runtime.h>

// ---------------------------------------------------------------------------
// DCINet: 3-layer GraphSAGE (mean aggr) + degree embedding encoder + MLP head.
// N=50000, E=800000, H=128.
// R11: head fused into layer-3 gemm (h3 tile lives in the retired sWl LDS
//      region; no h3 global round-trip, one fewer launch). Rest as R10.
//      Aggregate is at the reuse-2 LLC ceiling (~62% L2 hit) — left as is.
// ---------------------------------------------------------------------------

#define HDIM 128
#define NB 256          // binning blocks
#define MAXBUK 512      // max buckets (N <= 65536)
#define SCH 4096        // elements per scan block (256 thr x 16)

typedef __attribute__((ext_vector_type(8))) short short8;   // 8 bf16 (4 VGPR)
typedef __attribute__((ext_vector_type(4))) float f32x4;

__device__ inline float bf2f(unsigned short u) {
    union { unsigned int u; float f; } t; t.u = (unsigned int)u << 16; return t.f;
}
__device__ inline unsigned short f2bf(float f) {           // round-to-nearest-even
    union { float f; unsigned int u; } t; t.f = f;
    unsigned int u = t.u;
    return (unsigned short)((u + 0x7FFFu + ((u >> 16) & 1u)) >> 16);
}

// ---- phase 1: per-block LDS histograms over buckets (dst and src keys) -----

__global__ __launch_bounds__(256) void binhist_kernel(const int* __restrict__ src,
                                                      const int* __restrict__ dst,
                                                      int* __restrict__ hist,
                                                      int E, int nbuk, int ec) {
    __shared__ int hD[MAXBUK], hS[MAXBUK];
    const int tid = threadIdx.x, bid = blockIdx.x;
    for (int i = tid; i < nbuk; i += 256) { hD[i] = 0; hS[i] = 0; }
    __syncthreads();
    const int s0 = bid * ec, s1 = min(E, s0 + ec);
    for (int e = s0 + tid; e < s1; e += 256) {
        atomicAdd(&hD[dst[e] >> 7], 1);
        atomicAdd(&hS[src[e] >> 7], 1);
    }
    __syncthreads();
    for (int i = tid; i < nbuk; i += 256) {
        hist[(size_t)i * NB + bid] = hD[i];
        hist[(size_t)(nbuk + i) * NB + bid] = hS[i];
    }
}

// ---- phase 2: chunk sums, then per-chunk scan with in-kernel base ----------

__global__ __launch_bounds__(256) void hscan1_kernel(const int* __restrict__ a,
                                                     int* __restrict__ bsum, int L) {
    __shared__ int shw[4];
    const int tid = threadIdx.x;
    const int base = blockIdx.x * SCH + tid * 16;
    int s = 0;
#pragma unroll
    for (int j = 0; j < 16; ++j) { int i = base + j; if (i < L) s += a[i]; }
#pragma unroll
    for (int off = 32; off > 0; off >>= 1) s += __shfl_down(s, off, 64);
    if ((tid & 63) == 0) shw[tid >> 6] = s;
    __syncthreads();
    if (tid == 0) bsum[blockIdx.x] = shw[0] + shw[1] + shw[2] + shw[3];
}

__global__ __launch_bounds__(256) void hscan3_kernel(const int* __restrict__ a,
                                                     const int* __restrict__ bsum,
                                                     int* __restrict__ out, int L) {
    __shared__ int shw[4];
    __shared__ int sBase;
    const int tid = threadIdx.x;
    const int lane = tid & 63;
    const int w = tid >> 6;
    if (tid < 64) {                      // wave 0: base = sum of preceding chunks
        int v = (lane < blockIdx.x) ? bsum[lane] : 0;
#pragma unroll
        for (int off = 32; off > 0; off >>= 1) v += __shfl_down(v, off, 64);
        if (lane == 0) sBase = v;
    }
    const int base = blockIdx.x * SCH + tid * 16;
    int v[16];
    int s = 0;
#pragma unroll
    for (int j = 0; j < 16; ++j) {
        int i = base + j;
        v[j] = (i < L) ? a[i] : 0;
        s += v[j];
    }
    int incl = s;
#pragma unroll
    for (int off = 1; off < 64; off <<= 1) {
        int t = __shfl_up(incl, off, 64);
        if (lane >= off) incl += t;
    }
    if (lane == 63) shw[w] = incl;
    __syncthreads();
    int woff = 0;
#pragma unroll
    for (int j = 0; j < 4; ++j) if (j < w) woff += shw[j];
    int pfx = sBase + woff + incl - s;
#pragma unroll
    for (int j = 0; j < 16; ++j) {
        int i = base + j;
        if (i < L) out[i] = pfx;
        pfx += v[j];
    }
}

// ---- phase 3: scatter edges into bucket-sorted arrays (LDS cursors) --------

__global__ __launch_bounds__(256) void binscatter_kernel(const int* __restrict__ src,
                                                         const int* __restrict__ dst,
                                                         const int* __restrict__ scanned,
                                                         unsigned int* __restrict__ binD,
                                                         unsigned char* __restrict__ binS,
                                                         int E, int nbuk, int ec) {
    __shared__ int curD[MAXBUK], curS[MAXBUK];
    const int tid = threadIdx.x, bid = blockIdx.x;
    for (int i = tid; i < nbuk; i += 256) {
        curD[i] = scanned[(size_t)i * NB + bid];
        curS[i] = scanned[(size_t)(nbuk + i) * NB + bid] - E;
    }
    __syncthreads();
    const int s0 = bid * ec, s1 = min(E, s0 + ec);
    for (int e = s0 + tid; e < s1; e += 256) {
        int s = src[e], d = dst[e];
        int pd = atomicAdd(&curD[d >> 7], 1);
        binD[pd] = (unsigned int)s | ((unsigned int)(d & 127) << 16);
        int ps = atomicAdd(&curS[s >> 7], 1);
        binS[ps] = (unsigned char)(s & 127);
    }
}

// ---- phase 4: per-bucket finalize -> rowptr, outdeg, u16 CSR ---------------

__global__ __launch_bounds__(256) void finalize_kernel(const unsigned int* __restrict__ binD,
                                                       const unsigned char* __restrict__ binS,
                                                       const int* __restrict__ scanned,
                                                       unsigned short* __restrict__ csr,
                                                       int* __restrict__ rowptr,
                                                       int* __restrict__ outdeg,
                                                       int E, int n, int nbuk) {
    __shared__ int cntD[128], cur[128], cntS[128];
    const int b = blockIdx.x, tid = threadIdx.x;
    if (tid < 128) { cntD[tid] = 0; cntS[tid] = 0; }
    __syncthreads();
    const int s0 = scanned[(size_t)b * NB];
    const int s1 = (b == nbuk - 1) ? E : scanned[(size_t)(b + 1) * NB];
    const int t0 = scanned[(size_t)(nbuk + b) * NB] - E;
    const int t1 = (b == nbuk - 1) ? E : scanned[(size_t)(nbuk + b + 1) * NB] - E;
    for (int e = s0 + tid; e < s1; e += 256) atomicAdd(&cntD[(binD[e] >> 16) & 127], 1);
    for (int e = t0 + tid; e < t1; e += 256) atomicAdd(&cntS[binS[e]], 1);
    __syncthreads();
    if (tid < 128) cur[tid] = cntD[tid];
    __syncthreads();
    for (int off = 1; off < 128; off <<= 1) {
        int t = (tid < 128 && tid >= off) ? cur[tid - off] : 0;
        __syncthreads();
        if (tid < 128) cur[tid] += t;
        __syncthreads();
    }
    if (tid < 128) {
        int ex = cur[tid] - cntD[tid];
        int node = b * 128 + tid;
        if (node < n) { rowptr[node] = s0 + ex; outdeg[node] = cntS[tid]; }
        cur[tid] = ex;
    }
    __syncthreads();
    for (int e = s0 + tid; e < s1; e += 256) {
        unsigned int p = binD[e];
        int pos = atomicAdd(&cur[(p >> 16) & 127], 1);
        csr[s0 + pos] = (unsigned short)(p & 0xFFFFu);
    }
    if (b == 0 && tid == 0) rowptr[n] = E;
}

// ---- weight fp32 -> bf16: 6x[128][128] + Wh1[64][128], row-major kept ------

__global__ void wconv_kernel(const float* __restrict__ W1l, const float* __restrict__ W1r,
                             const float* __restrict__ W2l, const float* __restrict__ W2r,
                             const float* __restrict__ W3l, const float* __restrict__ W3r,
                             const float* __restrict__ Wh1,
                             unsigned short* __restrict__ out) {
    int idx = blockIdx.x * 256 + threadIdx.x;
    const float* s;
    int o;
    if (idx < 98304) {
        int m = idx >> 14; o = idx & 16383;
        switch (m) {
            case 0: s = W1l; break; case 1: s = W1r; break;
            case 2: s = W2l; break; case 3: s = W2r; break;
            case 4: s = W3l; break; default: s = W3r; break;
        }
    } else {
        s = Wh1; o = idx - 98304;
    }
    out[idx] = f2bf(s[o]);
}

// ---- encoder: h = relu(x*Wenc + benc + deg_emb[min(outdeg,199)]) -> bf16 ---

__global__ void encoder_kernel(const float* __restrict__ x, const float* __restrict__ Wenc,
                               const float* __restrict__ benc, const float* __restrict__ demb,
                               const int* __restrict__ outdeg,
                               unsigned short* __restrict__ h, int n) {
    int idx = blockIdx.x * blockDim.x + threadIdx.x;   // over n*16
    if (idx >= n * 16) return;
    int i = idx >> 4, g = idx & 15;
    int d = outdeg[i]; if (d > 199) d = 199;
    float xv = x[i];
    const float* wp = Wenc + g * 8;
    const float* bp = benc + g * 8;
    const float* ep = demb + (size_t)d * HDIM + g * 8;
    short8 o;
#pragma unroll
    for (int j = 0; j < 8; ++j)
        o[j] = (short)f2bf(fmaxf(xv * wp[j] + bp[j] + ep[j], 0.f));
    *(short8*)(h + (size_t)i * HDIM + g * 8) = o;
}

// ---- mean aggregation: 4 nodes per wave (16 lanes each), 8-deep unroll -----

__global__ __launch_bounds__(256) void aggregate_kernel(const unsigned short* __restrict__ hin,
                                                        const int* __restrict__ row_ptr,
                                                        const unsigned short* __restrict__ csr,
                                                        unsigned short* __restrict__ agg, int n) {
    const int tid = threadIdx.x;
    const int i = blockIdx.x * 16 + (tid >> 4);
    if (i >= n) return;
    const int l16 = tid & 15;
    const int beg = row_ptr[i], end = row_ptr[i + 1];
    float a[8] = {};
    for (int e = beg; e < end; e += 8) {
        short8 v[8];
#pragma unroll
        for (int u = 0; u < 8; ++u) {                 // 8 loads in flight
            int ee = e + u; if (ee > end - 1) ee = end - 1;
            int sidx = csr[ee];
            v[u] = *(const short8*)(hin + (size_t)sidx * HDIM + l16 * 8);
        }
#pragma unroll
        for (int u = 0; u < 8; ++u) {
            if (e + u < end) {
#pragma unroll
                for (int k = 0; k < 8; ++k)
                    a[k] += bf2f((unsigned short)v[u][k]);
            }
        }
    }
    float inv = 1.f / fmaxf((float)(end - beg), 1.f);
    short8 o;
#pragma unroll
    for (int j = 0; j < 8; ++j) o[j] = (short)f2bf(a[j] * inv);
    *(short8*)(agg + (size_t)i * HDIM + l16 * 8) = o;
}

// ---- MFMA SAGE linear (+ optional fused MLP head on layer 3) ---------------
// Swapped operands; weights staged in LDS once per block (XOR-swizzled chunks).
// Block = 4 waves; wave = 32 rows; K = 128. HEAD: h3 tile -> sW[0] (retired
// Wl region), then z=relu(h3@Wh1^T+bh1), scores=z@Wh2+bh2; no h3 in global.

template <bool RES, bool HEAD>
__global__ __launch_bounds__(256) void gemm_mfma(const unsigned short* __restrict__ agg,
                                                 const unsigned short* __restrict__ hin,
                                                 const unsigned short* __restrict__ Wl,
                                                 const unsigned short* __restrict__ Wr,
                                                 const float* __restrict__ bias,
                                                 unsigned short* __restrict__ outBf, int n,
                                                 const unsigned short* __restrict__ Wh1b,
                                                 const float* __restrict__ bh1,
                                                 const float* __restrict__ Wh2,
                                                 const float* __restrict__ bh2,
                                                 float* __restrict__ scores) {
    __shared__ unsigned short sW[2][128][128];      // [0]=Wl (later h3), [1]=Wr
    const int t = threadIdx.x;

    // stage weights: 2048 chunks of 8 bf16 each matrix; swizzle chunk ^= row&7
    for (int i = t; i < 2048; i += 256) {
        int r = i >> 4, cc = i & 15;
        int sc = (cc ^ (r & 7)) * 8;
        *(short8*)(&sW[0][r][sc]) = *(const short8*)(Wl + (size_t)r * HDIM + cc * 8);
        *(short8*)(&sW[1][r][sc]) = *(const short8*)(Wr + (size_t)r * HDIM + cc * 8);
    }
    __syncthreads();

    const int l = t & 63;
    const int wv = t >> 6;
    const int l16 = l & 15;
    const int q = l >> 4;                       // k-group / col-quad index 0..3
    const int swz = l16 & 7;
    const int row0 = blockIdx.x * 128 + wv * 32;
    const int node0 = min(row0 + l16, n - 1);
    const int node1 = min(row0 + 16 + l16, n - 1);

    const unsigned short* ap0 = agg + (size_t)node0 * HDIM + q * 8;
    const unsigned short* hp0 = hin + (size_t)node0 * HDIM + q * 8;
    const unsigned short* ap1 = agg + (size_t)node1 * HDIM + q * 8;
    const unsigned short* hp1 = hin + (size_t)node1 * HDIM + q * 8;

    f32x4 acc[2][8] = {};
#pragma unroll
    for (int k0 = 0; k0 < 128; k0 += 32) {
        short8 xa0 = *(const short8*)(ap0 + k0);
        short8 xh0 = *(const short8*)(hp0 + k0);
        short8 xa1 = *(const short8*)(ap1 + k0);
        short8 xh1 = *(const short8*)(hp1 + k0);
        const int ch = q + (k0 >> 3);
        const int sc = (ch ^ swz) * 8;
#pragma unroll
        for (int ct = 0; ct < 8; ++ct) {
            short8 bl = *(const short8*)(&sW[0][ct * 16 + l16][sc]);
            short8 br = *(const short8*)(&sW[1][ct * 16 + l16][sc]);
            acc[0][ct] = __builtin_amdgcn_mfma_f32_16x16x32_bf16(bl, xa0, acc[0][ct], 0, 0, 0);
            acc[0][ct] = __builtin_amdgcn_mfma_f32_16x16x32_bf16(br, xh0, acc[0][ct], 0, 0, 0);
            acc[1][ct] = __builtin_amdgcn_mfma_f32_16x16x32_bf16(bl, xa1, acc[1][ct], 0, 0, 0);
            acc[1][ct] = __builtin_amdgcn_mfma_f32_16x16x32_bf16(br, xh1, acc[1][ct], 0, 0, 0);
        }
    }

    if (HEAD) __syncthreads();          // everyone done reading sW[0]

#pragma unroll
    for (int ng = 0; ng < 2; ++ng) {
        int node = row0 + ng * 16 + l16;
        int lrow = wv * 32 + ng * 16 + l16;         // block-relative row
        int cnode = min(node, n - 1);
#pragma unroll
        for (int ct = 0; ct < 8; ++ct) {
            const int c0 = ct * 16 + q * 4;
            float4 bv = *(const float4*)(bias + c0);
            float v0 = fmaxf(acc[ng][ct][0] + bv.x, 0.f);
            float v1 = fmaxf(acc[ng][ct][1] + bv.y, 0.f);
            float v2 = fmaxf(acc[ng][ct][2] + bv.z, 0.f);
            float v3 = fmaxf(acc[ng][ct][3] + bv.w, 0.f);
            if (RES) {
                const unsigned short* rp = hin + (size_t)cnode * HDIM + c0;
                uint2 rv = *(const uint2*)rp;
                v0 += bf2f((unsigned short)(rv.x & 0xFFFF));
                v1 += bf2f((unsigned short)(rv.x >> 16));
                v2 += bf2f((unsigned short)(rv.y & 0xFFFF));
                v3 += bf2f((unsigned short)(rv.y >> 16));
            }
            unsigned int o0 = (unsigned int)f2bf(v0) | ((unsigned int)f2bf(v1) << 16);
            unsigned int o1 = (unsigned int)f2bf(v2) | ((unsigned int)f2bf(v3) << 16);
            uint2 o; o.x = o0; o.y = o1;
            if (HEAD) {
                // h3 -> LDS tile (chunk-swizzled); ch = c0/8, sub-off (q&1)*4
                const int ch = 2 * ct + (q >> 1);
                *(uint2*)(&sW[0][lrow][((ch ^ (lrow & 7)) * 8) + (q & 1) * 4]) = o;
            } else if (node < n) {
                *(uint2*)(outBf + (size_t)node * HDIM + c0) = o;
            }
        }
    }
    if (!HEAD) return;

    // ---- fused head: z = relu(h3@Wh1^T + bh1); score = z@Wh2 + bh2 ----
    __syncthreads();
    const unsigned short* whp = Wh1b + (size_t)l16 * HDIM + q * 8;
    const float bh2v = bh2[0];
#pragma unroll
    for (int ng = 0; ng < 2; ++ng) {
        const int lrow = wv * 32 + ng * 16 + l16;
        const int lswz = lrow & 7;
        f32x4 hacc[4] = {};
#pragma unroll
        for (int k0 = 0; k0 < 128; k0 += 32) {
            const int ch = q + (k0 >> 3);
            short8 xf = *(const short8*)(&sW[0][lrow][(ch ^ lswz) * 8]);
#pragma unroll
            for (int ct = 0; ct < 4; ++ct) {
                short8 wf = *(const short8*)(whp + (size_t)ct * 16 * HDIM + k0);
                hacc[ct] = __builtin_amdgcn_mfma_f32_16x16x32_bf16(wf, xf, hacc[ct], 0, 0, 0);
            }
        }
        float p = 0.f;
#pragma unroll
        for (int ct = 0; ct < 4; ++ct) {
            const int c0 = ct * 16 + q * 4;
            float4 b1 = *(const float4*)(bh1 + c0);
            float4 w2 = *(const float4*)(Wh2 + c0);
            p += fmaxf(hacc[ct][0] + b1.x, 0.f) * w2.x;
            p += fmaxf(hacc[ct][1] + b1.y, 0.f) * w2.y;
            p += fmaxf(hacc[ct][2] + b1.z, 0.f) * w2.z;
            p += fmaxf(hacc[ct][3] + b1.w, 0.f) * w2.w;
        }
        p += __shfl_xor(p, 16, 64);
        p += __shfl_xor(p, 32, 64);
        int node = row0 + ng * 16 + l16;
        if (q == 0 && node < n) scores[node] = p + bh2v;
    }
}

// ---------------------------------------------------------------------------

extern "C" void kernel_launch(void* const* d_in, const int* in_sizes, int n_in,
                              void* d_out, int out_size, void* d_ws, size_t ws_size,
                              hipStream_t stream) {
    const int N = in_sizes[0];
    const int E = in_sizes[1] / 2;
    const int H = HDIM;

    const float* x    = (const float*)d_in[0];
    const int*   ei   = (const int*)d_in[1];
    const int*   src  = ei;
    const int*   dst  = ei + E;
    const float* Wenc = (const float*)d_in[2];
    const float* benc = (const float*)d_in[3];
    const float* demb = (const float*)d_in[4];
    const float* W1l  = (const float*)d_in[5];
    const float* b1l  = (const float*)d_in[6];
    const float* W1r  = (const float*)d_in[7];
    const float* W2l  = (const float*)d_in[8];
    const float* b2l  = (const float*)d_in[9];
    const float* W2r  = (const float*)d_in[10];
    const float* W3l  = (const float*)d_in[11];
    const float* b3l  = (const float*)d_in[12];
    const float* W3r  = (const float*)d_in[13];
    const float* Wh1  = (const float*)d_in[14];
    const float* bh1  = (const float*)d_in[15];
    const float* Wh2  = (const float*)d_in[16];
    const float* bh2  = (const float*)d_in[17];

    const int nbuk = (N + 127) >> 7;
    const int L    = 2 * nbuk * NB;
    const int nbk  = (L + SCH - 1) / SCH;
    const int ec   = (E + NB - 1) / NB;

    size_t off = 0;
    char* base = (char*)d_ws;
    auto carve = [&](size_t bytes) -> char* {
        char* p = base + off;
        off += (bytes + 255) & ~(size_t)255;
        return p;
    };
    unsigned short* bufA = (unsigned short*)carve((size_t)N * H * 2);
    unsigned short* bufB = (unsigned short*)carve((size_t)N * H * 2);
    unsigned short* bufC = (unsigned short*)carve((size_t)N * H * 2);
    unsigned short* csr  = (unsigned short*)carve((size_t)E * 2);
    int*   rowptr  = (int*)carve((size_t)(N + 1) * 4);
    int*   outdeg  = (int*)carve((size_t)N * 4);
    int*   bsum    = (int*)carve(4096);
    int*   hist    = (int*)carve((size_t)L * 4);
    int*   scanned = (int*)carve((size_t)L * 4);
    unsigned int*  binD = (unsigned int*)carve((size_t)E * 4);
    unsigned char* binS = (unsigned char*)carve((size_t)E);
    unsigned short* Wb  = (unsigned short*)carve((size_t)(6 * H * H + 64 * H) * 2);
    (void)ws_size; (void)n_in; (void)out_size;

    unsigned short* W1lb = Wb;
    unsigned short* W1rb = Wb + 1 * H * H;
    unsigned short* W2lb = Wb + 2 * H * H;
    unsigned short* W2rb = Wb + 3 * H * H;
    unsigned short* W3lb = Wb + 4 * H * H;
    unsigned short* W3rb = Wb + 5 * H * H;
    unsigned short* Wh1b = Wb + 6 * H * H;

    // 1) CSR build — LDS counting sort, no global atomics
    binhist_kernel<<<NB, 256, 0, stream>>>(src, dst, hist, E, nbuk, ec);
    hscan1_kernel<<<nbk, 256, 0, stream>>>(hist, bsum, L);
    hscan3_kernel<<<nbk, 256, 0, stream>>>(hist, bsum, scanned, L);
    binscatter_kernel<<<NB, 256, 0, stream>>>(src, dst, scanned, binD, binS, E, nbuk, ec);
    finalize_kernel<<<nbuk, 256, 0, stream>>>(binD, binS, scanned, csr, rowptr, outdeg,
                                              E, N, nbuk);

    // 2) weights -> bf16 (row-major kept; includes Wh1)
    wconv_kernel<<<(6 * H * H + 64 * H) / 256, 256, 0, stream>>>(
        W1l, W1r, W2l, W2r, W3l, W3r, Wh1, Wb);

    // 3) encoder -> bufA (bf16)
    encoder_kernel<<<((size_t)N * 16 + 255) / 256, 256, 0, stream>>>(
        x, Wenc, benc, demb, outdeg, bufA, N);

    const int gAgg  = (N + 15) / 16;
    const int gGemm = (N + 127) / 128;

    // 4) layer 1: h1 = relu(sage(h))            A -> B -> C
    aggregate_kernel<<<gAgg, 256, 0, stream>>>(bufA, rowptr, csr, bufB, N);
    gemm_mfma<false, false><<<gGemm, 256, 0, stream>>>(bufB, bufA, W1lb, W1rb, b1l, bufC, N,
                                                       nullptr, nullptr, nullptr, nullptr,
                                                       nullptr);

    // 5) layer 2: h2 = relu(sage(h1)) + h1      C -> B -> A
    aggregate_kernel<<<gAgg, 256, 0, stream>>>(bufC, rowptr, csr, bufB, N);
    gemm_mfma<true, false><<<gGemm, 256, 0, stream>>>(bufB, bufC, W2lb, W2rb, b2l, bufA, N,
                                                      nullptr, nullptr, nullptr, nullptr,
                                                      nullptr);

    // 6) layer 3 + head: scores = head(relu(sage(h2)) + h2)   A -> B -> d_out
    aggregate_kernel<<<gAgg, 256, 0, stream>>>(bufA, rowptr, csr, bufB, N);
    gemm_mfma<true, true><<<gGemm, 256, 0, stream>>>(bufB, bufA, W3lb, W3rb, b3l, nullptr, N,
                                                     Wh1b, bh1, Wh2, bh2, (float*)d_out);
}